// Round 1
// baseline (645.822 us; speedup 1.0000x reference)
//
#include <hip/hip_runtime.h>

#define B_   32
#define H_   112
#define W_   112
#define C_   192
#define HW_  (H_*W_)      // 12544
#define BC_  (B_*C_)      // 6144
#define NPIX (B_*HW_)     // 401408
#define NF4  (B_*HW_*C_/4) // 19267584 float4s

__device__ __forceinline__ float sigmoidf_(float v) {
    return 1.0f / (1.0f + __expf(-v));
}

// monotonic float<->uint mapping for atomicMax on floats
__device__ __forceinline__ unsigned f2mono(float f) {
    unsigned u = __float_as_uint(f);
    return (u & 0x80000000u) ? ~u : (u | 0x80000000u);
}
__device__ __forceinline__ float mono2f(unsigned u) {
    return __uint_as_float((u & 0x80000000u) ? (u & 0x7FFFFFFFu) : ~u);
}

__global__ __launch_bounds__(256) void k_init(float* gsum, unsigned* gmax) {
    int i = blockIdx.x * 256 + threadIdx.x;
    if (i < BC_) { gsum[i] = 0.0f; gmax[i] = 0u; }  // 0u decodes below any real float
}

// One block per (b,h) row. Computes:
//  - per-(b,c) sum & max partials -> atomics into gsum/gmax
//  - per-pixel channel mean & max -> avg_sp/max_sp
__global__ __launch_bounds__(256) void k_pool(const float* __restrict__ x,
                                              float* __restrict__ gsum,
                                              unsigned* __restrict__ gmax,
                                              float* __restrict__ avg_sp,
                                              float* __restrict__ max_sp) {
    const int t   = threadIdx.x;
    const int row = blockIdx.x;          // b*H_ + h
    const int b   = row / H_;
    const float4* xr = (const float4*)(x + (size_t)row * (W_ * C_)); // 112*48 float4

    // ---- Loop A: per-channel accumulation (240 active threads, fixed c4) ----
    float4 s4 = {0.f, 0.f, 0.f, 0.f};
    float4 m4 = {-3.0e38f, -3.0e38f, -3.0e38f, -3.0e38f};
    const int c4 = t % 48;
    const int g  = t / 48;
    if (t < 240) {
        for (int p = g; p < W_; p += 5) {
            float4 v = xr[p * 48 + c4];
            s4.x += v.x; s4.y += v.y; s4.z += v.z; s4.w += v.w;
            m4.x = fmaxf(m4.x, v.x); m4.y = fmaxf(m4.y, v.y);
            m4.z = fmaxf(m4.z, v.z); m4.w = fmaxf(m4.w, v.w);
        }
    }

    // ---- Loop B: per-pixel channel reduction, 16 lanes per pixel (L2 re-read) ----
    const int sub = t & 15;
    const int pg  = t >> 4;
    for (int k = 0; k < 7; ++k) {
        const int p = pg + 16 * k;       // 16*7 == 112, exact
        float4 a = xr[p * 48 + sub];
        float4 c = xr[p * 48 + sub + 16];
        float4 d = xr[p * 48 + sub + 32];
        float s = (a.x + a.y + a.z + a.w) + (c.x + c.y + c.z + c.w) + (d.x + d.y + d.z + d.w);
        float m = fmaxf(fmaxf(fmaxf(a.x, a.y), fmaxf(a.z, a.w)),
                 fmaxf(fmaxf(fmaxf(c.x, c.y), fmaxf(c.z, c.w)),
                       fmaxf(fmaxf(d.x, d.y), fmaxf(d.z, d.w))));
        #pragma unroll
        for (int sh = 1; sh < 16; sh <<= 1) {
            s += __shfl_xor(s, sh, 64);
            m = fmaxf(m, __shfl_xor(m, sh, 64));
        }
        if (sub == 0) {
            const int pix = row * W_ + p;   // b*HW_ + h*W_ + p
            avg_sp[pix] = s * (1.0f / C_);
            max_sp[pix] = m;
        }
    }

    // ---- LDS reduce of loop A partials, then global atomics ----
    __shared__ float4 ls[240];
    __shared__ float4 lm[240];
    if (t < 240) { ls[t] = s4; lm[t] = m4; }
    __syncthreads();
    if (t < 48) {
        float4 S = ls[t], M = lm[t];
        #pragma unroll
        for (int gg = 1; gg < 5; ++gg) {
            float4 o = ls[t + 48 * gg];
            S.x += o.x; S.y += o.y; S.z += o.z; S.w += o.w;
            float4 om = lm[t + 48 * gg];
            M.x = fmaxf(M.x, om.x); M.y = fmaxf(M.y, om.y);
            M.z = fmaxf(M.z, om.z); M.w = fmaxf(M.w, om.w);
        }
        float* gs = gsum + b * C_ + t * 4;
        atomicAdd(gs + 0, S.x); atomicAdd(gs + 1, S.y);
        atomicAdd(gs + 2, S.z); atomicAdd(gs + 3, S.w);
        unsigned* gm = gmax + b * C_ + t * 4;
        atomicMax(gm + 0, f2mono(M.x)); atomicMax(gm + 1, f2mono(M.y));
        atomicMax(gm + 2, f2mono(M.z)); atomicMax(gm + 3, f2mono(M.w));
    }
}

// SE + CBAM channel MLPs; one block per batch, 192 threads.
// scale[b,c] = sigmoid(SE) * sigmoid(mlp(avg)+mlp(max))
__global__ __launch_bounds__(192) void k_small(const float* __restrict__ gsum,
                                               const unsigned* __restrict__ gmax,
                                               const float* __restrict__ se_w1,
                                               const float* __restrict__ se_b1,
                                               const float* __restrict__ se_w2,
                                               const float* __restrict__ se_b2,
                                               const float* __restrict__ mlp_w1,
                                               const float* __restrict__ mlp_b1,
                                               const float* __restrict__ mlp_w2,
                                               const float* __restrict__ mlp_b2,
                                               float* __restrict__ scale) {
    const int b = blockIdx.x, t = threadIdx.x;
    __shared__ float avg[C_], mx[C_], hse[12], ha[24], hm[24];
    avg[t] = gsum[b * C_ + t] * (1.0f / HW_);
    mx[t]  = mono2f(gmax[b * C_ + t]);
    __syncthreads();
    if (t < 12) {
        float z = se_b1[t];
        for (int c = 0; c < C_; ++c) z += avg[c] * se_w1[c * 12 + t];
        hse[t] = z * sigmoidf_(z);          // swish
    }
    if (t < 24) {
        float za = mlp_b1[t], zm = mlp_b1[t];
        for (int c = 0; c < C_; ++c) {
            float w = mlp_w1[c * 24 + t];
            za += avg[c] * w;
            zm += mx[c] * w;
        }
        ha[t] = za * sigmoidf_(za);
        hm[t] = zm * sigmoidf_(zm);
    }
    __syncthreads();
    float sv = se_b2[t];
    #pragma unroll
    for (int j = 0; j < 12; ++j) sv += hse[j] * se_w2[j * C_ + t];
    float av = 2.0f * mlp_b2[t];            // mlp(avg)+mlp(max): bias twice
    #pragma unroll
    for (int j = 0; j < 24; ++j) av += (ha[j] + hm[j]) * mlp_w2[j * C_ + t];
    scale[b * C_ + t] = sigmoidf_(sv) * sigmoidf_(av);
}

// 7x7 SAME conv over [avg_sp, max_sp] -> sigmoid -> satt
__global__ __launch_bounds__(256) void k_conv(const float* __restrict__ avg_sp,
                                              const float* __restrict__ max_sp,
                                              const float* __restrict__ conv_k,
                                              const float* __restrict__ conv_b,
                                              float* __restrict__ satt) {
    __shared__ float lk[98];
    __shared__ float lb;
    const int t = threadIdx.x;
    if (t < 98) lk[t] = conv_k[t];
    if (t == 0) lb = conv_b[0];
    __syncthreads();
    const int idx = blockIdx.x * 256 + t;
    if (idx >= NPIX) return;
    const int b  = idx / HW_;
    const int r  = idx % HW_;
    const int y  = r / W_;
    const int x0 = r % W_;
    const float* ab = avg_sp + b * HW_;
    const float* mb = max_sp + b * HW_;
    float acc = lb;
    #pragma unroll
    for (int dy = 0; dy < 7; ++dy) {
        const int yy = y + dy - 3;
        if (yy < 0 || yy >= H_) continue;
        #pragma unroll
        for (int dx = 0; dx < 7; ++dx) {
            const int xx = x0 + dx - 3;
            if (xx < 0 || xx >= W_) continue;
            const int o = yy * W_ + xx;
            acc += ab[o] * lk[(dy * 7 + dx) * 2] + mb[o] * lk[(dy * 7 + dx) * 2 + 1];
        }
    }
    satt[idx] = sigmoidf_(acc);
}

// out = x * scale[b,c] * satt[b,h,w], float4 over channels
__global__ __launch_bounds__(256) void k_apply(const float4* __restrict__ x4,
                                               const float* __restrict__ scale,
                                               const float* __restrict__ satt,
                                               float4* __restrict__ out4) {
    const int idx = blockIdx.x * 256 + threadIdx.x;
    if (idx >= NF4) return;
    const int pix = idx / 48;
    const int c4  = idx - pix * 48;
    const int b   = pix / HW_;
    const float ss = satt[pix];
    const float4 sc = ((const float4*)scale)[b * 48 + c4];
    float4 v = x4[idx];
    float4 o;
    o.x = v.x * sc.x * ss;
    o.y = v.y * sc.y * ss;
    o.z = v.z * sc.z * ss;
    o.w = v.w * sc.w * ss;
    out4[idx] = o;
}

extern "C" void kernel_launch(void* const* d_in, const int* in_sizes, int n_in,
                              void* d_out, int out_size, void* d_ws, size_t ws_size,
                              hipStream_t stream) {
    const float* x      = (const float*)d_in[0];
    const float* se_w1  = (const float*)d_in[1];
    const float* se_b1  = (const float*)d_in[2];
    const float* se_w2  = (const float*)d_in[3];
    const float* se_b2  = (const float*)d_in[4];
    const float* mlp_w1 = (const float*)d_in[5];
    const float* mlp_b1 = (const float*)d_in[6];
    const float* mlp_w2 = (const float*)d_in[7];
    const float* mlp_b2 = (const float*)d_in[8];
    const float* conv_k = (const float*)d_in[9];
    const float* conv_b = (const float*)d_in[10];
    float* out = (float*)d_out;

    float*    ws     = (float*)d_ws;
    float*    gsum   = ws;                       // 6144 floats
    unsigned* gmax   = (unsigned*)(ws + 6144);   // 6144 uints
    float*    scale  = ws + 12288;               // 6144 floats (16B aligned)
    float*    avg_sp = ws + 18432;               // 401408 floats
    float*    max_sp = ws + 419840;              // 401408 floats
    float*    satt   = ws + 821248;              // 401408 floats

    k_init <<<(BC_ + 255) / 256, 256, 0, stream>>>(gsum, gmax);
    k_pool <<<B_ * H_, 256, 0, stream>>>(x, gsum, gmax, avg_sp, max_sp);
    k_small<<<B_, 192, 0, stream>>>(gsum, gmax, se_w1, se_b1, se_w2, se_b2,
                                    mlp_w1, mlp_b1, mlp_w2, mlp_b2, scale);
    k_conv <<<(NPIX + 255) / 256, 256, 0, stream>>>(avg_sp, max_sp, conv_k, conv_b, satt);
    k_apply<<<NF4 / 256, 256, 0, stream>>>((const float4*)x, scale, satt, (float4*)out);
}